// Round 4
// baseline (200.955 us; speedup 1.0000x reference)
//
#include <hip/hip_runtime.h>
#include <stdint.h>

// out[b,s,n] = int32(sum_k x[b,s,k]*w[n,k]) * (scale_i*scale_w[n]) + bias[n]
// Harness materializes integer inputs as int32. Pack to int8 in d_ws, then
// int8 MFMA GEMM: 128x128 tile, BK=128, v_mfma_i32_32x32x32_i8, 3 blocks/CU.
#define M_DIM 8192
#define N_DIM 4096
#define K_DIM 1024
#define BK    128

using i32x4  = __attribute__((ext_vector_type(4))) int;
using i32x16 = __attribute__((ext_vector_type(16))) int;

// ---- fused pack pass: int32 (low byte) -> int8, 16 ints per thread ----
__global__ __launch_bounds__(256) void pack_both(const int* __restrict__ X32,
                                                 const int* __restrict__ W32,
                                                 int* __restrict__ Xp,
                                                 int* __restrict__ Wp) {
    int b = blockIdx.x;
    const int4* s4;
    int4* d4;
    int u;
    if (b < 2048) {            // X: 2097152 packed dwords, 4/thread
        u  = b * 256 + threadIdx.x;
        s4 = (const int4*)X32;
        d4 = (int4*)Xp;
    } else {                   // W: 1048576 packed dwords
        u  = (b - 2048) * 256 + threadIdx.x;
        s4 = (const int4*)W32;
        d4 = (int4*)Wp;
    }
    int4 o;
    #pragma unroll
    for (int i = 0; i < 4; ++i) {
        int4 v = s4[u * 4 + i];
        ((int*)&o)[i] = (v.x & 0xFF) | ((v.y & 0xFF) << 8) |
                        ((v.z & 0xFF) << 16) | (v.w << 24);
    }
    d4[u] = o;
}

// async global->LDS, 16B per lane. LDS dest is wave-uniform base + lane*16.
__device__ __forceinline__ void cp16_async(const void* g, void* l) {
    __builtin_amdgcn_global_load_lds(
        (const __attribute__((address_space(1))) void*)g,
        (__attribute__((address_space(3))) void*)l,
        16, 0, 0);
}

// 128x128 tile, BK=128, 256 threads = 4 waves (2x2), 64x64 per wave,
// 2x2 tiles of 32x32, 4 K-steps of 32 per K-tile (16 MFMAs/iter/wave).
__global__ __launch_bounds__(256, 3) void i8gemm_dequant(
    const int8_t* __restrict__ X,        // [M, K] packed int8
    const int8_t* __restrict__ W,        // [N, K] packed int8
    const float*  __restrict__ scale_i,  // [1]
    const float*  __restrict__ scale_w,  // [N]
    const float*  __restrict__ bias,     // [N]
    float*        __restrict__ out)      // [M, N]
{
    __shared__ int8_t lA[128 * BK];   // 16 KB
    __shared__ int8_t lB[128 * BK];   // 16 KB

    const int t     = threadIdx.x;
    const int lane  = t & 63;
    const int wave  = t >> 6;
    const int waveM = wave >> 1;
    const int waveN = wave & 1;

    const int bm = blockIdx.y * 128;
    const int bn = blockIdx.x * 128;

    i32x16 acc[2][2] = {};   // 64 VGPRs

    // staging: chunk c in [0,1024): LDS addr c*16; row=c>>3, qlds=c&7,
    // content = logical quad q = qlds ^ (row&7)  (XOR swizzle over 8-chunk row)
    const int8_t* Asrc[4];
    const int8_t* Bsrc[4];
    int8_t* dA[4];
    int8_t* dB[4];
    #pragma unroll
    for (int s = 0; s < 4; ++s) {
        int c   = t + 256 * s;
        int row = c >> 3;
        int q   = (c & 7) ^ (row & 7);
        Asrc[s] = X + (size_t)(bm + row) * K_DIM + q * 16;
        Bsrc[s] = W + (size_t)(bn + row) * K_DIM + q * 16;
        dA[s]   = lA + (256 * s + wave * 64) * 16;   // wave-uniform; HW adds lane*16
        dB[s]   = lB + (256 * s + wave * 64) * 16;
    }

    // fragment reads for 32x32x32 i8: A-operand lane l holds
    // m = l&31, k-bytes [ (l>>5)*16, +16 ) within the 32-wide k-step.
    // logical quad q = s*2 + (lane>>5); addr = r*BK + (q^(r&7))*16
    int aoff[4][2], boff[4][2];
    #pragma unroll
    for (int s = 0; s < 4; ++s) {
        #pragma unroll
        for (int i = 0; i < 2; ++i) {
            int r = waveM * 64 + i * 32 + (lane & 31);
            int q = (s * 2 + (lane >> 5)) ^ (r & 7);
            aoff[s][i] = r * BK + q * 16;
        }
        #pragma unroll
        for (int j = 0; j < 2; ++j) {
            int r = waveN * 64 + j * 32 + (lane & 31);
            int q = (s * 2 + (lane >> 5)) ^ (r & 7);
            boff[s][j] = r * BK + q * 16;
        }
    }

    for (int k0 = 0; k0 < K_DIM; k0 += BK) {
        #pragma unroll
        for (int s = 0; s < 4; ++s) {
            cp16_async(Asrc[s] + k0, dA[s]);
            cp16_async(Bsrc[s] + k0, dB[s]);
        }
        __syncthreads();

        i32x4 af[4][2], bf[4][2];
        #pragma unroll
        for (int s = 0; s < 4; ++s) {
            #pragma unroll
            for (int i = 0; i < 2; ++i) af[s][i] = *(const i32x4*)(lA + aoff[s][i]);
            #pragma unroll
            for (int j = 0; j < 2; ++j) bf[s][j] = *(const i32x4*)(lB + boff[s][j]);
        }

        #pragma unroll
        for (int s = 0; s < 4; ++s)
            #pragma unroll
            for (int i = 0; i < 2; ++i)
                #pragma unroll
                for (int j = 0; j < 2; ++j)
                    acc[i][j] = __builtin_amdgcn_mfma_i32_32x32x32_i8(
                        af[s][i], bf[s][j], acc[i][j], 0, 0, 0);

        __syncthreads();
    }

    // epilogue: 32x32 C/D layout: col = lane&31,
    // row = (reg&3) + 8*(reg>>2) + 4*(lane>>5)
    const float si = scale_i[0];
    float s[2], b[2];
    int   ncol[2];
    #pragma unroll
    for (int j = 0; j < 2; ++j) {
        ncol[j] = bn + waveN * 64 + j * 32 + (lane & 31);
        s[j] = si * scale_w[ncol[j]];
        b[j] = bias[ncol[j]];
    }
    const int rbase = 4 * (lane >> 5);
    #pragma unroll
    for (int i = 0; i < 2; ++i) {
        int mbase = bm + waveM * 64 + i * 32 + rbase;
        #pragma unroll
        for (int reg = 0; reg < 16; ++reg) {
            int m = mbase + (reg & 3) + 8 * (reg >> 2);
            size_t rowoff = (size_t)m * N_DIM;
            #pragma unroll
            for (int j = 0; j < 2; ++j) {
                out[rowoff + ncol[j]] = (float)acc[i][j][reg] * s[j] + b[j];
            }
        }
    }
}

extern "C" void kernel_launch(void* const* d_in, const int* in_sizes, int n_in,
                              void* d_out, int out_size, void* d_ws, size_t ws_size,
                              hipStream_t stream) {
    const int* x32 = (const int*)d_in[0];   // [M,K] int32
    const int* w32 = (const int*)d_in[1];   // [N,K] int32
    const float* si = (const float*)d_in[2];
    const float* sw = (const float*)d_in[3];
    const float* bs = (const float*)d_in[4];
    float* out = (float*)d_out;

    int8_t* Xp = (int8_t*)d_ws;                              // 8 MB
    int8_t* Wp = (int8_t*)d_ws + (size_t)M_DIM * K_DIM;      // 4 MB

    pack_both<<<3072, 256, 0, stream>>>(x32, w32, (int*)Xp, (int*)Wp);

    dim3 grid(N_DIM / 128, M_DIM / 128);   // 32 x 64 blocks
    i8gemm_dequant<<<grid, 256, 0, stream>>>(Xp, Wp, si, sw, bs, out);
}